// Round 3
// baseline (4540.982 us; speedup 1.0000x reference)
//
#include <hip/hip_runtime.h>
#include <cstdio>

// ============================================================================
// DecoderGenerator: 2-layer LSTM decoder + additive attention + big vocab
// projection + NLL, fully fused on-device.
//
//   1. prep_kernel     : bf16-cast weights/enc, gather embeddings, transpose
//                        enc, init h-state buffers, zero barrier ctrl.
//   2. a0_kernel       : A0 = xs @ W_ih0^T + b  (hoisted layer-0 input GEMM),
//                        stored bf16 with bias folded.
//   3. lstm_kernel     : persistent 64-WG kernel, 129 ticks with a custom
//                        agent-scope grid barrier; MFMA recurrent matmuls.
//   4. phpe_kernel     : ph = Hall@Wh^T ; pe = enc@We^T + attn_b
//   5. logits_kernel   : logits[t,b,l] = sum_k v_w[k] tanh(ph+pe)
//   6. att_kernel      : softmax over b (axis=1 of (T,B,L) — per reference!)
//   7. weighted_kernel : weighted = att @ enc  (per-batch GEMM) -> G[:,512:]
//   8. fc_kernel       : fused GEMM (G @ fc_W^T) + per-row (max,sumexp)
//                        partials; fc_W streamed from HBM exactly once.
//   9. tgt_kernel      : target logits z_y per row
//  10. finalize_kernel : logsumexp merge + masked-mean NLL -> d_out[0]
//
// Round-3 fix: attn_W halves are 512x512 = 262144 elements each (NOT 524288).
// The old NA=524288 read 2 MB past the end of attn_W -> GPU page fault ->
// the observed "Aborted (core dumped)". Prep grid resized to match exactly.
// ============================================================================

#define DI __device__ __forceinline__

typedef __attribute__((ext_vector_type(8))) short short8;
typedef __attribute__((ext_vector_type(4))) float floatx4;

#define TSEQ   128
#define VOCAB  32000
#define GDIM   2048   // 4*H
#define NROW   2048   // B*T
#define KFC    1024   // 2*H

// ---------------- small helpers ----------------
DI float bf2f(unsigned short u) {
    union { unsigned u; float f; } x; x.u = ((unsigned)u) << 16; return x.f;
}
DI unsigned short f2bf(float f) {   // RNE float -> bf16
    unsigned u = __float_as_uint(f);
    unsigned r = (u + 0x7FFF + ((u >> 16) & 1)) >> 16;
    return (unsigned short)r;
}
DI short8 ld8(const unsigned short* p) { return *(const short8*)p; }
DI floatx4 mfma16(short8 a, short8 b, floatx4 c) {
    return __builtin_amdgcn_mfma_f32_16x16x32_bf16(a, b, c, 0, 0, 0);
}
DI float sigm(float x) { return __builtin_amdgcn_rcpf(1.f + __expf(-x)); }
DI float tanh_f(float x) {
    float xc = fminf(8.f, fmaxf(-8.f, x));
    float e  = __expf(2.f * xc);
    return (e - 1.f) * __builtin_amdgcn_rcpf(e + 1.f);
}

// ---------------- grid barrier (agent scope, sense via generation) --------
DI void gbar(int* ctrl, int nwg) {
    __threadfence();
    __syncthreads();
    if (threadIdx.x == 0) {
        int* cnt = ctrl;
        int* gen = ctrl + 1;
        int g = __hip_atomic_load(gen, __ATOMIC_RELAXED, __HIP_MEMORY_SCOPE_AGENT);
        int a = __hip_atomic_fetch_add(cnt, 1, __ATOMIC_ACQ_REL, __HIP_MEMORY_SCOPE_AGENT);
        if (a == nwg - 1) {
            __hip_atomic_store(cnt, 0, __ATOMIC_RELAXED, __HIP_MEMORY_SCOPE_AGENT);
            __hip_atomic_fetch_add(gen, 1, __ATOMIC_RELEASE, __HIP_MEMORY_SCOPE_AGENT);
        } else {
            int guard = 0;
            while (__hip_atomic_load(gen, __ATOMIC_ACQUIRE, __HIP_MEMORY_SCOPE_AGENT) == g) {
                __builtin_amdgcn_s_sleep(1);
                if (++guard > (1 << 22)) break;   // fail loud, not hung
            }
        }
    }
    __syncthreads();
    __threadfence();
}

// fallback path: make the failure visible instead of faulting
__global__ void zero_out_kernel(float* out, int n) {
    int i = blockIdx.x * 64 + threadIdx.x;
    if (i < n) out[i] = 0.f;
}

// ============================================================================
// 1. prep kernel : segmented grid-stride over all conversion jobs
//    total work = 4*1048576 + 2*262144 + 3*1048576 + 16384 = 7,880,704
//    grid = 7,880,704 / 256 = 30,784 blocks exactly.
// ============================================================================
__global__ void prep_kernel(const int* X, const float* enc, const float* emb,
                            const float* Wih0, const float* Whh0,
                            const float* Wih1, const float* Whh1,
                            const float* attnW, const float* h0,
                            unsigned short* wih0b, unsigned short* whh0b,
                            unsigned short* wih1b, unsigned short* whh1b,
                            unsigned short* whb, unsigned short* web,
                            unsigned short* encb, unsigned short* enctb,
                            unsigned short* xsb,
                            unsigned short* h0buf, unsigned short* h1buf,
                            int* ctrl) {
    if (blockIdx.x == 0 && threadIdx.x < 64) ctrl[threadIdx.x] = 0;  // barrier state
    long i = (long)blockIdx.x * 256 + threadIdx.x;
    const long NW = 1048576;
    const long NA = 262144;            // 512x512 half of attn_W (FIXED: was 524288)
    if (i < NW) { wih0b[i] = f2bf(Wih0[i]); return; } i -= NW;
    if (i < NW) { whh0b[i] = f2bf(Whh0[i]); return; } i -= NW;
    if (i < NW) { wih1b[i] = f2bf(Wih1[i]); return; } i -= NW;
    if (i < NW) { whh1b[i] = f2bf(Whh1[i]); return; } i -= NW;
    if (i < NA) { long k = i >> 9, h = i & 511; whb[i] = f2bf(attnW[k * 1024 + h]);       return; } i -= NA;
    if (i < NA) { long k = i >> 9, h = i & 511; web[i] = f2bf(attnW[k * 1024 + 512 + h]); return; } i -= NA;
    if (i < NW) { encb[i] = f2bf(enc[i]); return; } i -= NW;
    if (i < NW) {  // enc_t[b][h][l] = enc[b][l][h]
        long b = i >> 16, r = i & 65535, h = r >> 7, l = r & 127;
        enctb[i] = f2bf(enc[(b * 128 + l) * 512 + h]); return;
    } i -= NW;
    if (i < NW) {  // xs[t*16+b][e] = emb[X[b][t]][e]
        long m = i >> 9, e = i & 511, t = m >> 4, b = m & 15;
        int xi = X[b * 129 + t];
        xi = (xi < 0) ? 0 : ((xi >= VOCAB) ? VOCAB - 1 : xi);   // defensive
        xsb[i] = f2bf(emb[(long)xi * 512 + e]); return;
    } i -= NW;
    if (i < 16384) {  // h inits into parity-1 buffers
        long layer = i >> 13, r = i & 8191;
        unsigned short v = f2bf(h0[layer * 8192 + r]);
        if (layer == 0) h0buf[8192 + r] = v; else h1buf[8192 + r] = v;
    }
}

// ============================================================================
// shared 64x64 MFMA tile: C[m0..+63][n0..+63] += A(m,k) * B(n,k)^T
// wave w -> rows m0+w*16, 4 n-tiles.  A,B bf16 row-major along k.
// ============================================================================
DI void gemm64_acc(const unsigned short* A, const unsigned short* Bw,
                   int m0, int n0, int lda, int ldb, int nkb, floatx4 acc[4]) {
    int tid = threadIdx.x;
    int wv = tid >> 6, ln = tid & 63;
    int colL = ln & 15, koff = (ln >> 4) * 8;
    const unsigned short* ar  = A  + (size_t)(m0 + wv * 16 + colL) * lda + koff;
    const unsigned short* br0 = Bw + (size_t)(n0 +  0 + colL) * ldb + koff;
    const unsigned short* br1 = Bw + (size_t)(n0 + 16 + colL) * ldb + koff;
    const unsigned short* br2 = Bw + (size_t)(n0 + 32 + colL) * ldb + koff;
    const unsigned short* br3 = Bw + (size_t)(n0 + 48 + colL) * ldb + koff;
    for (int kb = 0; kb < nkb; ++kb) {
        short8 af = ld8(ar + kb * 32);
        acc[0] = mfma16(af, ld8(br0 + kb * 32), acc[0]);
        acc[1] = mfma16(af, ld8(br1 + kb * 32), acc[1]);
        acc[2] = mfma16(af, ld8(br2 + kb * 32), acc[2]);
        acc[3] = mfma16(af, ld8(br3 + kb * 32), acc[3]);
    }
}

// 2. A0 = xs @ W_ih0^T + (b_ih0 + b_hh0), stored bf16 (bias folded)
__global__ void a0_kernel(const unsigned short* xs, const unsigned short* wih0b,
                          const float* bih0, const float* bhh0, unsigned short* A0b) {
    floatx4 acc[4] = {{0,0,0,0},{0,0,0,0},{0,0,0,0},{0,0,0,0}};
    int m0 = blockIdx.x * 64, n0 = blockIdx.y * 64;
    gemm64_acc(xs, wih0b, m0, n0, 512, 512, 16, acc);
    int tid = threadIdx.x, wv = tid >> 6, ln = tid & 63, colL = ln & 15, q = ln >> 4;
    int mrow = m0 + wv * 16;
#pragma unroll
    for (int nt = 0; nt < 4; ++nt) {
        int col = n0 + nt * 16 + colL;
        float bb = bih0[col] + bhh0[col];
#pragma unroll
        for (int r = 0; r < 4; ++r)
            A0b[(size_t)(mrow + q * 4 + r) * GDIM + col] = f2bf(acc[nt][r] + bb);
    }
}

// ============================================================================
// 3. persistent LSTM kernel.  64 WGs: 0..31 layer0, 32..63 layer1.
//    tick t: L0 computes h0[t], L1 computes h1[t-1].  One barrier per tick.
// ============================================================================
__global__ __launch_bounds__(256, 1)
void lstm_kernel(const unsigned short* A0b,
                 const unsigned short* whh0b, const unsigned short* wih1b,
                 const unsigned short* whh1b,
                 const float* bih1, const float* bhh1, const float* c0in,
                 unsigned short* h0buf, unsigned short* h1buf,
                 unsigned short* Hall, unsigned short* Gmat, int* ctrl) {
    __shared__ float gbuf[4][16][16];   // [gate][batch][unit]
    int wg = blockIdx.x;
    int tid = threadIdx.x, wv = tid >> 6, ln = tid & 63;
    bool isL1 = (wg >= 32);
    int u0 = (isL1 ? wg - 32 : wg) * 16;      // hidden-unit slice base
    int n0 = wv * 512 + u0;                   // gate column base (wave = gate)
    int colL = ln & 15, q = ln >> 4, koff = q * 8;
    int eb = tid >> 4, eu = tid & 15;         // elementwise mapping
    float c = c0in[(isL1 ? 1 : 0) * 8192 + eb * 512 + u0 + eu];
    float bias1 = isL1 ? (bih1[n0 + colL] + bhh1[n0 + colL]) : 0.f;

    const unsigned short* wr0 = whh0b + (size_t)(n0 + colL) * 512 + koff;
    const unsigned short* wr1 = wih1b + (size_t)(n0 + colL) * 512 + koff;
    const unsigned short* wr2 = whh1b + (size_t)(n0 + colL) * 512 + koff;

#pragma unroll 1
    for (int t = 0; t <= TSEQ; ++t) {
        bool act = isL1 ? (t >= 1) : (t < TSEQ);
        if (act) {
            floatx4 acc;
            if (!isL1) {
                const unsigned short* a0r = A0b + (size_t)(t * 16) * GDIM + n0 + colL;
                acc[0] = bf2f(a0r[(q * 4 + 0) * GDIM]);
                acc[1] = bf2f(a0r[(q * 4 + 1) * GDIM]);
                acc[2] = bf2f(a0r[(q * 4 + 2) * GDIM]);
                acc[3] = bf2f(a0r[(q * 4 + 3) * GDIM]);
                const unsigned short* hp = h0buf + ((t - 1) & 1) * 8192 + colL * 512 + koff;
#pragma unroll
                for (int kb = 0; kb < 16; ++kb)
                    acc = mfma16(ld8(hp + kb * 32), ld8(wr0 + kb * 32), acc);
            } else {
                int s = t - 1;
                acc[0] = bias1; acc[1] = bias1; acc[2] = bias1; acc[3] = bias1;
                const unsigned short* hp0 = h0buf + (s & 1) * 8192 + colL * 512 + koff;
#pragma unroll
                for (int kb = 0; kb < 16; ++kb)
                    acc = mfma16(ld8(hp0 + kb * 32), ld8(wr1 + kb * 32), acc);
                const unsigned short* hp1 = h1buf + ((s - 1) & 1) * 8192 + colL * 512 + koff;
#pragma unroll
                for (int kb = 0; kb < 16; ++kb)
                    acc = mfma16(ld8(hp1 + kb * 32), ld8(wr2 + kb * 32), acc);
            }
            // D layout: row = batch = q*4+r, col = unit = colL
            gbuf[wv][q * 4 + 0][colL] = acc[0];
            gbuf[wv][q * 4 + 1][colL] = acc[1];
            gbuf[wv][q * 4 + 2][colL] = acc[2];
            gbuf[wv][q * 4 + 3][colL] = acc[3];
        }
        __syncthreads();
        if (act) {
            float gi = gbuf[0][eb][eu], gf = gbuf[1][eb][eu];
            float gg = gbuf[2][eb][eu], go = gbuf[3][eb][eu];
            float c2 = sigm(gf) * c + sigm(gi) * tanh_f(gg);
            float h2 = sigm(go) * tanh_f(c2);
            c = c2;
            unsigned short hb = f2bf(h2);
            if (!isL1) {
                h0buf[(t & 1) * 8192 + eb * 512 + u0 + eu] = hb;
            } else {
                int s = t - 1;
                h1buf[(s & 1) * 8192 + eb * 512 + u0 + eu] = hb;
                Hall[(size_t)(s * 16 + eb) * 512 + u0 + eu] = hb;           // [t*16+b][u]
                Gmat[(size_t)(eb * 128 + s) * KFC + u0 + eu] = hb;          // [b*128+t][u]
            }
        }
        gbar(ctrl, 64);
    }
}

// 4. ph = Hall @ Wh^T ; pe = enc @ We^T + attn_b   (z selects)
__global__ void phpe_kernel(const unsigned short* Hall, const unsigned short* encb,
                            const unsigned short* whb, const unsigned short* web,
                            const float* attnb, float* ph, float* pe) {
    bool ispe = (blockIdx.z != 0);
    const unsigned short* A  = ispe ? encb : Hall;
    const unsigned short* Bw = ispe ? web  : whb;
    float* out = ispe ? pe : ph;
    floatx4 acc[4] = {{0,0,0,0},{0,0,0,0},{0,0,0,0},{0,0,0,0}};
    int m0 = blockIdx.x * 64, n0 = blockIdx.y * 64;
    gemm64_acc(A, Bw, m0, n0, 512, 512, 16, acc);
    int tid = threadIdx.x, wv = tid >> 6, ln = tid & 63, colL = ln & 15, q = ln >> 4;
    int mrow = m0 + wv * 16;
#pragma unroll
    for (int nt = 0; nt < 4; ++nt) {
        int col = n0 + nt * 16 + colL;
        float bb = ispe ? attnb[col] : 0.f;
#pragma unroll
        for (int r = 0; r < 4; ++r)
            out[(size_t)(mrow + q * 4 + r) * 512 + col] = acc[nt][r] + bb;
    }
}

// 5. logits[t][l][b] = sum_k v_w[k] * tanh(ph[t*16+b][k] + pe[b*128+l][k])
__global__ void logits_kernel(const float* ph, const float* pe, const float* vw,
                              float* logits) {
    int m = blockIdx.x;             // t*16+b
    int t = m >> 4, b = m & 15;
    int tid = threadIdx.x, wv = tid >> 6, ln = tid & 63;
    const float* phr = ph + (size_t)m * 512 + ln * 8;
    floatx4 ph0 = *(const floatx4*)phr;
    floatx4 ph1 = *(const floatx4*)(phr + 4);
    const float* vwr = vw + ln * 8;
    floatx4 vw0 = *(const floatx4*)vwr;
    floatx4 vw1 = *(const floatx4*)(vwr + 4);
    for (int li = 0; li < 32; ++li) {
        int ll = wv * 32 + li;
        const float* per = pe + (size_t)(b * 128 + ll) * 512 + ln * 8;
        floatx4 p0 = *(const floatx4*)per;
        floatx4 p1 = *(const floatx4*)(per + 4);
        float s = 0.f;
#pragma unroll
        for (int j = 0; j < 4; ++j) s += vw0[j] * tanh_f(ph0[j] + p0[j]);
#pragma unroll
        for (int j = 0; j < 4; ++j) s += vw1[j] * tanh_f(ph1[j] + p1[j]);
#pragma unroll
        for (int off = 32; off; off >>= 1) s += __shfl_xor(s, off, 64);
        if (ln == 0) logits[((size_t)t * 128 + ll) * 16 + b] = s;
    }
}

// 6. softmax over b (axis=1 of (T,B,L) — matches reference!) -> att_bf16[b][t][l]
__global__ void att_kernel(const float* logits, unsigned short* attb) {
    int t = blockIdx.x, l = threadIdx.x;     // 128 threads
    const float* p = logits + ((size_t)t * 128 + l) * 16;
    float x[16], mx = -1e30f;
#pragma unroll
    for (int j = 0; j < 16; ++j) { x[j] = p[j]; mx = fmaxf(mx, x[j]); }
    float s = 0.f;
#pragma unroll
    for (int j = 0; j < 16; ++j) { x[j] = __expf(x[j] - mx); s += x[j]; }
    float inv = __builtin_amdgcn_rcpf(s);
#pragma unroll
    for (int j = 0; j < 16; ++j)
        attb[((size_t)j * 128 + t) * 128 + l] = f2bf(x[j] * inv);
}

// 7. weighted[b][t][h] = att[b] @ enc[b]  ->  G[b*128+t][512+h]
__global__ void weighted_kernel(const unsigned short* attb, const unsigned short* enctb,
                                unsigned short* Gmat) {
    int b = blockIdx.z;
    floatx4 acc[4] = {{0,0,0,0},{0,0,0,0},{0,0,0,0},{0,0,0,0}};
    int m0 = blockIdx.x * 64, n0 = blockIdx.y * 64;
    gemm64_acc(attb + (size_t)b * 128 * 128, enctb + (size_t)b * 512 * 128,
               m0, n0, 128, 128, 4, acc);
    int tid = threadIdx.x, wv = tid >> 6, ln = tid & 63, colL = ln & 15, q = ln >> 4;
    int mrow = m0 + wv * 16;
#pragma unroll
    for (int nt = 0; nt < 4; ++nt) {
        int col = n0 + nt * 16 + colL;
#pragma unroll
        for (int r = 0; r < 4; ++r)
            Gmat[(size_t)(b * 128 + mrow + q * 4 + r) * KFC + 512 + col] = f2bf(acc[nt][r]);
    }
}

// ============================================================================
// 8. fc GEMM + fused per-row (max, sumexp) partials.
//    250 WGs x 512 threads.  Each WG: all 2048 rows x 128 cols.
//    fc_W slice register-cached bf16 (read from HBM exactly once).
// ============================================================================
__global__ __launch_bounds__(512, 2)
void fc_kernel(const unsigned short* G, const float* fcW, const float* fcb,
               float2* partials) {
    int wgn = blockIdx.x;
    int tid = threadIdx.x, wv = tid >> 6, ln = tid & 63;
    int colL = ln & 15, q = ln >> 4, koff = q * 8;
    int n0 = wgn * 128 + wv * 16;
    const float* wrow = fcW + (size_t)(n0 + colL) * KFC + koff;
    short8 Bf[32];
#pragma unroll
    for (int kb = 0; kb < 32; ++kb) {
        short8 v;
#pragma unroll
        for (int j = 0; j < 8; ++j) v[j] = (short)f2bf(wrow[kb * 32 + j]);
        Bf[kb] = v;
    }
    float cb = fcb[n0 + colL];
    __shared__ float2 pbuf[128][8];

    for (int mb = 0; mb < 16; ++mb) {
        floatx4 acc[8];
#pragma unroll
        for (int mt = 0; mt < 8; ++mt) acc[mt] = (floatx4){0,0,0,0};
        const unsigned short* gbase =
            G + (size_t)(mb * 128 + colL) * KFC + koff;
#pragma unroll
        for (int kb = 0; kb < 32; ++kb) {
#pragma unroll
            for (int mt = 0; mt < 8; ++mt) {
                short8 af = ld8(gbase + (size_t)mt * 16 * KFC + kb * 32);
                acc[mt] = mfma16(af, Bf[kb], acc[mt]);
            }
        }
        __syncthreads();   // pbuf reuse guard vs previous mb's merge
        // epilogue: per row (16 cols of this wave) -> (max, sumexp)
#pragma unroll
        for (int mt = 0; mt < 8; ++mt) {
#pragma unroll
            for (int r = 0; r < 4; ++r) {
                float v = acc[mt][r] + cb;
                float M = v;
#pragma unroll
                for (int off = 1; off < 16; off <<= 1) M = fmaxf(M, __shfl_xor(M, off, 64));
                float e = __expf(v - M);
#pragma unroll
                for (int off = 1; off < 16; off <<= 1) e += __shfl_xor(e, off, 64);
                if (colL == 0) pbuf[mt * 16 + q * 4 + r][wv] = make_float2(M, e);
            }
        }
        __syncthreads();
        if (tid < 128) {   // merge 8 waves -> one partial per (row, WG)
            float2 a = pbuf[tid][0];
            float M = a.x, S = a.y;
#pragma unroll
            for (int w = 1; w < 8; ++w) {
                float2 p = pbuf[tid][w];
                float nm = fmaxf(M, p.x);
                S = S * __expf(M - nm) + p.y * __expf(p.x - nm);
                M = nm;
            }
            partials[(size_t)(mb * 128 + tid) * 250 + wgn] = make_float2(M, S);
        }
    }
}

// 9. target logit per row: z_y = G[r] . fc_W[y] + fc_b[y]
__global__ void tgt_kernel(const unsigned short* G, const float* fcW, const float* fcb,
                           const int* X, float* tgt) {
    int r = blockIdx.x * 4 + (threadIdx.x >> 6);
    int ln = threadIdx.x & 63;
    int b = r >> 7, t = r & 127;
    int y = X[b * 129 + t + 1];
    y = (y < 0) ? 0 : ((y >= VOCAB) ? VOCAB - 1 : y);   // defensive
    const unsigned short* g = G + (size_t)r * KFC;
    const float* w = fcW + (size_t)y * KFC;
    float s = 0.f;
    for (int j = ln; j < KFC; j += 64) s += bf2f(g[j]) * w[j];
#pragma unroll
    for (int off = 32; off; off >>= 1) s += __shfl_xor(s, off, 64);
    if (ln == 0) tgt[r] = s + fcb[y];
}

// 10. merge partials -> logsumexp -> masked mean NLL
__global__ void finalize_kernel(const float2* partials, const float* tgt,
                                const int* X, float* out) {
    int tid = threadIdx.x;
    float vs = 0.f, vc = 0.f;
    for (int r = tid; r < NROW; r += 256) {
        const float2* p = partials + (size_t)r * 250;
        float M = p[0].x, S = p[0].y;
        for (int i = 1; i < 250; ++i) {
            float2 qq = p[i];
            float nm = fmaxf(M, qq.x);
            S = S * __expf(M - nm) + qq.y * __expf(qq.x - nm);
            M = nm;
        }
        float lse = M + __logf(S);
        int b = r >> 7, t = r & 127;
        int y = X[b * 129 + t + 1];
        if (y != 0) { vs += lse - tgt[r]; vc += 1.f; }
    }
    __shared__ float sv[256], sc[256];
    sv[tid] = vs; sc[tid] = vc;
    __syncthreads();
    for (int s = 128; s; s >>= 1) {
        if (tid < s) { sv[tid] += sv[tid + s]; sc[tid] += sc[tid + s]; }
        __syncthreads();
    }
    if (tid == 0) out[0] = sv[0] / sc[0];
}

// ============================================================================
// launcher
// ============================================================================
extern "C" void kernel_launch(void* const* d_in, const int* in_sizes, int n_in,
                              void* d_out, int out_size, void* d_ws, size_t ws_size,
                              hipStream_t stream) {
    const int*   X     = (const int*)d_in[0];
    const float* enc   = (const float*)d_in[2];
    const float* emb   = (const float*)d_in[3];
    const float* Wih0  = (const float*)d_in[4];
    const float* Whh0  = (const float*)d_in[5];
    const float* bih0  = (const float*)d_in[6];
    const float* bhh0  = (const float*)d_in[7];
    const float* Wih1  = (const float*)d_in[8];
    const float* Whh1  = (const float*)d_in[9];
    const float* bih1  = (const float*)d_in[10];
    const float* bhh1  = (const float*)d_in[11];
    const float* attnW = (const float*)d_in[12];
    const float* attnb = (const float*)d_in[13];
    const float* vw    = (const float*)d_in[14];
    const float* fcW   = (const float*)d_in[15];
    const float* fcb   = (const float*)d_in[16];
    const float* h0    = (const float*)d_in[17];
    const float* c0    = (const float*)d_in[18];

    char* ws = (char*)d_ws;
    size_t off = 0;
    auto take = [&](size_t bytes) { char* p = ws + off; off += (bytes + 255) & ~(size_t)255; return p; };
    int*            ctrl    = (int*)           take(256);
    unsigned short* wih0b   = (unsigned short*)take(2097152);
    unsigned short* whh0b   = (unsigned short*)take(2097152);
    unsigned short* wih1b   = (unsigned short*)take(2097152);
    unsigned short* whh1b   = (unsigned short*)take(2097152);
    unsigned short* whb     = (unsigned short*)take(524288);
    unsigned short* web     = (unsigned short*)take(524288);
    unsigned short* encb    = (unsigned short*)take(2097152);
    unsigned short* enctb   = (unsigned short*)take(2097152);
    unsigned short* xsb     = (unsigned short*)take(2097152);
    unsigned short* h0buf   = (unsigned short*)take(32768);
    unsigned short* h1buf   = (unsigned short*)take(32768);
    unsigned short* A0b     = (unsigned short*)take(8388608);
    unsigned short* hallb   = (unsigned short*)take(2097152);
    unsigned short* gmat    = (unsigned short*)take(4194304);
    float*          ph      = (float*)         take(4194304);
    float*          pe      = (float*)         take(4194304);
    float*          logitsb = (float*)         take(1048576);
    unsigned short* attb    = (unsigned short*)take(524288);
    float2*         parts   = (float2*)        take(4096000);
    float*          tgt     = (float*)         take(8192);
    size_t need = off;
    (void)in_sizes; (void)n_in;

    fprintf(stderr, "[kernel_launch] ws_size=%zu need=%zu out_size=%d n_in=%d\n",
            ws_size, need, out_size, n_in);
    fflush(stderr);
    if (ws_size < need) {
        // Not enough scratch: fail visibly (absmax error) instead of faulting.
        hipLaunchKernelGGL(zero_out_kernel, dim3((out_size + 63) / 64), dim3(64),
                           0, stream, (float*)d_out, out_size);
        return;
    }

    hipLaunchKernelGGL(prep_kernel, dim3(30784), dim3(256), 0, stream,
                       X, enc, emb, Wih0, Whh0, Wih1, Whh1, attnW, h0,
                       wih0b, whh0b, wih1b, whh1b, whb, web, encb, enctb,
                       xsb, h0buf, h1buf, ctrl);
    hipLaunchKernelGGL(a0_kernel, dim3(32, 32), dim3(256), 0, stream,
                       xsb, wih0b, bih0, bhh0, A0b);
    hipLaunchKernelGGL(lstm_kernel, dim3(64), dim3(256), 0, stream,
                       A0b, whh0b, wih1b, whh1b, bih1, bhh1, c0,
                       h0buf, h1buf, hallb, gmat, ctrl);
    hipLaunchKernelGGL(phpe_kernel, dim3(32, 8, 2), dim3(256), 0, stream,
                       hallb, encb, whb, web, attnb, ph, pe);
    hipLaunchKernelGGL(logits_kernel, dim3(2048), dim3(256), 0, stream,
                       ph, pe, vw, logitsb);
    hipLaunchKernelGGL(att_kernel, dim3(128), dim3(128), 0, stream,
                       logitsb, attb);
    hipLaunchKernelGGL(weighted_kernel, dim3(2, 8, 16), dim3(256), 0, stream,
                       attb, enctb, gmat);
    hipLaunchKernelGGL(fc_kernel, dim3(250), dim3(512), 0, stream,
                       gmat, fcW, fcb, parts);
    hipLaunchKernelGGL(tgt_kernel, dim3(512), dim3(256), 0, stream,
                       gmat, fcW, fcb, X, tgt);
    hipLaunchKernelGGL(finalize_kernel, dim3(1), dim3(256), 0, stream,
                       parts, tgt, X, (float*)d_out);
}

// Round 4
// 3602.968 us; speedup vs baseline: 1.2603x; 1.2603x over previous
//
#include <hip/hip_runtime.h>

// ============================================================================
// DecoderGenerator: 2-layer LSTM decoder + additive attention + big vocab
// projection + NLL, fully fused on-device.
//
//   1. prep_kernel     : bf16-cast weights/enc, gather embeddings, transpose
//                        enc, init h-state buffers, zero barrier ctrl.
//   2. a0_kernel       : A0 = xs @ W_ih0^T + b  (hoisted layer-0 input GEMM)
//   3. lstm_kernel     : persistent 64-WG kernel, 129 ticks, grid barrier.
//                        ROUND 4: weights register-resident (loaded once),
//                        h vectors staged through LDS once per WG per tick.
//   4. phpe_kernel     : ph = Hall@Wh^T ; pe = enc@We^T + attn_b
//   5. logits_kernel   : logits[t,b,l] = sum_k v_w[k] tanh(ph+pe)
//   6. att_kernel      : softmax over b (axis=1 of (T,B,L) — per reference!)
//   7. weighted_kernel : weighted = att @ enc  (per-batch GEMM) -> G[:,512:]
//   8. fc_kernel       : fused GEMM (G @ fc_W^T) + per-row (max,sumexp)
//   9. tgt_kernel      : target logits z_y per row
//  10. finalize_kernel : logsumexp merge + masked-mean NLL -> d_out[0]
// ============================================================================

#define DI __device__ __forceinline__

typedef __attribute__((ext_vector_type(8))) short short8;
typedef __attribute__((ext_vector_type(4))) float floatx4;

#define TSEQ   128
#define VOCAB  32000
#define GDIM   2048   // 4*H
#define NROW   2048   // B*T
#define KFC    1024   // 2*H
#define HPAD   520    // LDS row stride for h staging (512 + 8 pad)

// ---------------- small helpers ----------------
DI float bf2f(unsigned short u) {
    union { unsigned u; float f; } x; x.u = ((unsigned)u) << 16; return x.f;
}
DI unsigned short f2bf(float f) {   // RNE float -> bf16
    unsigned u = __float_as_uint(f);
    unsigned r = (u + 0x7FFF + ((u >> 16) & 1)) >> 16;
    return (unsigned short)r;
}
DI short8 ld8(const unsigned short* p) { return *(const short8*)p; }
DI floatx4 mfma16(short8 a, short8 b, floatx4 c) {
    return __builtin_amdgcn_mfma_f32_16x16x32_bf16(a, b, c, 0, 0, 0);
}
DI float sigm(float x) { return __builtin_amdgcn_rcpf(1.f + __expf(-x)); }
DI float tanh_f(float x) {
    float xc = fminf(8.f, fmaxf(-8.f, x));
    float e  = __expf(2.f * xc);
    return (e - 1.f) * __builtin_amdgcn_rcpf(e + 1.f);
}

// ---------------- grid barrier (agent scope, sense via generation) --------
DI void gbar(int* ctrl, int nwg) {
    __threadfence();
    __syncthreads();
    if (threadIdx.x == 0) {
        int* cnt = ctrl;
        int* gen = ctrl + 1;
        int g = __hip_atomic_load(gen, __ATOMIC_RELAXED, __HIP_MEMORY_SCOPE_AGENT);
        int a = __hip_atomic_fetch_add(cnt, 1, __ATOMIC_ACQ_REL, __HIP_MEMORY_SCOPE_AGENT);
        if (a == nwg - 1) {
            __hip_atomic_store(cnt, 0, __ATOMIC_RELAXED, __HIP_MEMORY_SCOPE_AGENT);
            __hip_atomic_fetch_add(gen, 1, __ATOMIC_RELEASE, __HIP_MEMORY_SCOPE_AGENT);
        } else {
            int guard = 0;
            while (__hip_atomic_load(gen, __ATOMIC_ACQUIRE, __HIP_MEMORY_SCOPE_AGENT) == g) {
                __builtin_amdgcn_s_sleep(1);
                if (++guard > (1 << 22)) break;   // fail loud, not hung
            }
        }
    }
    __syncthreads();
    __threadfence();
}

// fallback path: make the failure visible instead of faulting
__global__ void zero_out_kernel(float* out, int n) {
    int i = blockIdx.x * 64 + threadIdx.x;
    if (i < n) out[i] = 0.f;
}

// ============================================================================
// 1. prep kernel : segmented grid-stride over all conversion jobs
//    total work = 4*1048576 + 2*262144 + 3*1048576 + 16384 = 7,880,704
//    grid = 30,784 blocks x 256.
// ============================================================================
__global__ void prep_kernel(const int* X, const float* enc, const float* emb,
                            const float* Wih0, const float* Whh0,
                            const float* Wih1, const float* Whh1,
                            const float* attnW, const float* h0,
                            unsigned short* wih0b, unsigned short* whh0b,
                            unsigned short* wih1b, unsigned short* whh1b,
                            unsigned short* whb, unsigned short* web,
                            unsigned short* encb, unsigned short* enctb,
                            unsigned short* xsb,
                            unsigned short* h0buf, unsigned short* h1buf,
                            int* ctrl) {
    if (blockIdx.x == 0 && threadIdx.x < 64) ctrl[threadIdx.x] = 0;  // barrier state
    long i = (long)blockIdx.x * 256 + threadIdx.x;
    const long NW = 1048576;
    const long NA = 262144;            // 512x512 half of attn_W
    if (i < NW) { wih0b[i] = f2bf(Wih0[i]); return; } i -= NW;
    if (i < NW) { whh0b[i] = f2bf(Whh0[i]); return; } i -= NW;
    if (i < NW) { wih1b[i] = f2bf(Wih1[i]); return; } i -= NW;
    if (i < NW) { whh1b[i] = f2bf(Whh1[i]); return; } i -= NW;
    if (i < NA) { long k = i >> 9, h = i & 511; whb[i] = f2bf(attnW[k * 1024 + h]);       return; } i -= NA;
    if (i < NA) { long k = i >> 9, h = i & 511; web[i] = f2bf(attnW[k * 1024 + 512 + h]); return; } i -= NA;
    if (i < NW) { encb[i] = f2bf(enc[i]); return; } i -= NW;
    if (i < NW) {  // enc_t[b][h][l] = enc[b][l][h]
        long b = i >> 16, r = i & 65535, h = r >> 7, l = r & 127;
        enctb[i] = f2bf(enc[(b * 128 + l) * 512 + h]); return;
    } i -= NW;
    if (i < NW) {  // xs[t*16+b][e] = emb[X[b][t]][e]
        long m = i >> 9, e = i & 511, t = m >> 4, b = m & 15;
        int xi = X[b * 129 + t];
        xi = (xi < 0) ? 0 : ((xi >= VOCAB) ? VOCAB - 1 : xi);   // defensive
        xsb[i] = f2bf(emb[(long)xi * 512 + e]); return;
    } i -= NW;
    if (i < 16384) {  // h inits into parity-1 buffers
        long layer = i >> 13, r = i & 8191;
        unsigned short v = f2bf(h0[layer * 8192 + r]);
        if (layer == 0) h0buf[8192 + r] = v; else h1buf[8192 + r] = v;
    }
}

// ============================================================================
// shared 64x64 MFMA tile: C[m0..+63][n0..+63] += A(m,k) * B(n,k)^T
// ============================================================================
DI void gemm64_acc(const unsigned short* A, const unsigned short* Bw,
                   int m0, int n0, int lda, int ldb, int nkb, floatx4 acc[4]) {
    int tid = threadIdx.x;
    int wv = tid >> 6, ln = tid & 63;
    int colL = ln & 15, koff = (ln >> 4) * 8;
    const unsigned short* ar  = A  + (size_t)(m0 + wv * 16 + colL) * lda + koff;
    const unsigned short* br0 = Bw + (size_t)(n0 +  0 + colL) * ldb + koff;
    const unsigned short* br1 = Bw + (size_t)(n0 + 16 + colL) * ldb + koff;
    const unsigned short* br2 = Bw + (size_t)(n0 + 32 + colL) * ldb + koff;
    const unsigned short* br3 = Bw + (size_t)(n0 + 48 + colL) * ldb + koff;
    for (int kb = 0; kb < nkb; ++kb) {
        short8 af = ld8(ar + kb * 32);
        acc[0] = mfma16(af, ld8(br0 + kb * 32), acc[0]);
        acc[1] = mfma16(af, ld8(br1 + kb * 32), acc[1]);
        acc[2] = mfma16(af, ld8(br2 + kb * 32), acc[2]);
        acc[3] = mfma16(af, ld8(br3 + kb * 32), acc[3]);
    }
}

// 2. A0 = xs @ W_ih0^T + (b_ih0 + b_hh0), stored bf16 (bias folded)
__global__ void a0_kernel(const unsigned short* xs, const unsigned short* wih0b,
                          const float* bih0, const float* bhh0, unsigned short* A0b) {
    floatx4 acc[4] = {{0,0,0,0},{0,0,0,0},{0,0,0,0},{0,0,0,0}};
    int m0 = blockIdx.x * 64, n0 = blockIdx.y * 64;
    gemm64_acc(xs, wih0b, m0, n0, 512, 512, 16, acc);
    int tid = threadIdx.x, wv = tid >> 6, ln = tid & 63, colL = ln & 15, q = ln >> 4;
    int mrow = m0 + wv * 16;
#pragma unroll
    for (int nt = 0; nt < 4; ++nt) {
        int col = n0 + nt * 16 + colL;
        float bb = bih0[col] + bhh0[col];
#pragma unroll
        for (int r = 0; r < 4; ++r)
            A0b[(size_t)(mrow + q * 4 + r) * GDIM + col] = f2bf(acc[nt][r] + bb);
    }
}

// ============================================================================
// 3. persistent LSTM kernel.  64 WGs: 0..31 layer0, 32..63 layer1.
//    tick t: L0 computes h0[t], L1 computes h1[t-1].  One barrier per tick.
//    Round 4: weight slices live in VGPRs (loaded once before the loop);
//    h vectors staged global->LDS once per WG per tick (coalesced),
//    MFMA A-fragments read from LDS (padded stride, conflict-free).
// ============================================================================
__global__ __launch_bounds__(256, 1)
void lstm_kernel(const unsigned short* A0b,
                 const unsigned short* whh0b, const unsigned short* wih1b,
                 const unsigned short* whh1b,
                 const float* bih1, const float* bhh1, const float* c0in,
                 unsigned short* h0buf, unsigned short* h1buf,
                 unsigned short* Hall, unsigned short* Gmat, int* ctrl) {
    __shared__ unsigned short hsh0[16 * HPAD];   // L0: h0[t-1] ; L1: h0[s]
    __shared__ unsigned short hsh1[16 * HPAD];   // L1 only: h1[s-1]
    __shared__ float gbuf[4][16][16];            // [gate][batch][unit]
    int wg = blockIdx.x;
    int tid = threadIdx.x, wv = tid >> 6, ln = tid & 63;
    bool isL1 = (wg >= 32);
    int u0 = (isL1 ? wg - 32 : wg) * 16;      // hidden-unit slice base
    int n0 = wv * 512 + u0;                   // gate column base (wave = gate)
    int colL = ln & 15, q = ln >> 4, koff = q * 8;
    int eb = tid >> 4, eu = tid & 15;         // elementwise mapping
    float c = c0in[(isL1 ? 1 : 0) * 8192 + eb * 512 + u0 + eu];
    float bias1 = isL1 ? (bih1[n0 + colL] + bhh1[n0 + colL]) : 0.f;

    // ---- one-time: weight slices into registers ----
    // L0 wave: rows n0..n0+15 of whh0b      -> w0r[16]  (64 VGPRs)
    // L1 wave: rows n0..n0+15 of wih1b,whh1b -> w1r,w2r (128 VGPRs)
    short8 w0r[16], w1r[16], w2r[16];
    if (!isL1) {
        const unsigned short* wr0 = whh0b + (size_t)(n0 + colL) * 512 + koff;
#pragma unroll
        for (int kb = 0; kb < 16; ++kb) w0r[kb] = ld8(wr0 + kb * 32);
    } else {
        const unsigned short* wr1 = wih1b + (size_t)(n0 + colL) * 512 + koff;
        const unsigned short* wr2 = whh1b + (size_t)(n0 + colL) * 512 + koff;
#pragma unroll
        for (int kb = 0; kb < 16; ++kb) w1r[kb] = ld8(wr1 + kb * 32);
#pragma unroll
        for (int kb = 0; kb < 16; ++kb) w2r[kb] = ld8(wr2 + kb * 32);
    }

#pragma unroll 1
    for (int t = 0; t <= TSEQ; ++t) {
        bool act = isL1 ? (t >= 1) : (t < TSEQ);
        floatx4 acc;
        // ---- stage h vectors global -> LDS (coalesced, once per WG) ----
        if (act) {
            if (!isL1) {
                const unsigned short* src = h0buf + ((t - 1) & 1) * 8192;
                short8 st[4];
#pragma unroll
                for (int j = 0; j < 4; ++j) st[j] = ld8(src + (j * 256 + tid) * 8);
#pragma unroll
                for (int j = 0; j < 4; ++j) {
                    int idx = (j * 256 + tid) * 8;
                    *(short8*)&hsh0[(idx >> 9) * HPAD + (idx & 511)] = st[j];
                }
                // A0 pre-activation (bias folded) into acc
                const unsigned short* a0r = A0b + (size_t)(t * 16) * GDIM + n0 + colL;
                acc[0] = bf2f(a0r[(q * 4 + 0) * GDIM]);
                acc[1] = bf2f(a0r[(q * 4 + 1) * GDIM]);
                acc[2] = bf2f(a0r[(q * 4 + 2) * GDIM]);
                acc[3] = bf2f(a0r[(q * 4 + 3) * GDIM]);
            } else {
                int s = t - 1;
                const unsigned short* s0 = h0buf + (s & 1) * 8192;
                const unsigned short* s1 = h1buf + ((s - 1) & 1) * 8192;
                short8 st0[4], st1[4];
#pragma unroll
                for (int j = 0; j < 4; ++j) st0[j] = ld8(s0 + (j * 256 + tid) * 8);
#pragma unroll
                for (int j = 0; j < 4; ++j) st1[j] = ld8(s1 + (j * 256 + tid) * 8);
#pragma unroll
                for (int j = 0; j < 4; ++j) {
                    int idx = (j * 256 + tid) * 8;
                    int o = (idx >> 9) * HPAD + (idx & 511);
                    *(short8*)&hsh0[o] = st0[j];
                    *(short8*)&hsh1[o] = st1[j];
                }
                acc[0] = bias1; acc[1] = bias1; acc[2] = bias1; acc[3] = bias1;
            }
        }
        __syncthreads();
        // ---- MFMA: LDS fragments x register weights ----
        if (act) {
            const unsigned short* hl0 = hsh0 + colL * HPAD + koff;
            if (!isL1) {
#pragma unroll
                for (int kb = 0; kb < 16; ++kb)
                    acc = mfma16(ld8(hl0 + kb * 32), w0r[kb], acc);
            } else {
                const unsigned short* hl1 = hsh1 + colL * HPAD + koff;
#pragma unroll
                for (int kb = 0; kb < 16; ++kb)
                    acc = mfma16(ld8(hl0 + kb * 32), w1r[kb], acc);
#pragma unroll
                for (int kb = 0; kb < 16; ++kb)
                    acc = mfma16(ld8(hl1 + kb * 32), w2r[kb], acc);
            }
            // D layout: row = batch = q*4+r, col = unit = colL
            gbuf[wv][q * 4 + 0][colL] = acc[0];
            gbuf[wv][q * 4 + 1][colL] = acc[1];
            gbuf[wv][q * 4 + 2][colL] = acc[2];
            gbuf[wv][q * 4 + 3][colL] = acc[3];
        }
        __syncthreads();
        if (act) {
            float gi = gbuf[0][eb][eu], gf = gbuf[1][eb][eu];
            float gg = gbuf[2][eb][eu], go = gbuf[3][eb][eu];
            float c2 = sigm(gf) * c + sigm(gi) * tanh_f(gg);
            float h2 = sigm(go) * tanh_f(c2);
            c = c2;
            unsigned short hb = f2bf(h2);
            if (!isL1) {
                h0buf[(t & 1) * 8192 + eb * 512 + u0 + eu] = hb;
            } else {
                int s = t - 1;
                h1buf[(s & 1) * 8192 + eb * 512 + u0 + eu] = hb;
                Hall[(size_t)(s * 16 + eb) * 512 + u0 + eu] = hb;           // [t*16+b][u]
                Gmat[(size_t)(eb * 128 + s) * KFC + u0 + eu] = hb;          // [b*128+t][u]
            }
        }
        gbar(ctrl, 64);
    }
}

// 4. ph = Hall @ Wh^T ; pe = enc @ We^T + attn_b   (z selects)
__global__ void phpe_kernel(const unsigned short* Hall, const unsigned short* encb,
                            const unsigned short* whb, const unsigned short* web,
                            const float* attnb, float* ph, float* pe) {
    bool ispe = (blockIdx.z != 0);
    const unsigned short* A  = ispe ? encb : Hall;
    const unsigned short* Bw = ispe ? web  : whb;
    float* out = ispe ? pe : ph;
    floatx4 acc[4] = {{0,0,0,0},{0,0,0,0},{0,0,0,0},{0,0,0,0}};
    int m0 = blockIdx.x * 64, n0 = blockIdx.y * 64;
    gemm64_acc(A, Bw, m0, n0, 512, 512, 16, acc);
    int tid = threadIdx.x, wv = tid >> 6, ln = tid & 63, colL = ln & 15, q = ln >> 4;
    int mrow = m0 + wv * 16;
#pragma unroll
    for (int nt = 0; nt < 4; ++nt) {
        int col = n0 + nt * 16 + colL;
        float bb = ispe ? attnb[col] : 0.f;
#pragma unroll
        for (int r = 0; r < 4; ++r)
            out[(size_t)(mrow + q * 4 + r) * 512 + col] = acc[nt][r] + bb;
    }
}

// 5. logits[t][l][b] = sum_k v_w[k] * tanh(ph[t*16+b][k] + pe[b*128+l][k])
__global__ void logits_kernel(const float* ph, const float* pe, const float* vw,
                              float* logits) {
    int m = blockIdx.x;             // t*16+b
    int t = m >> 4, b = m & 15;
    int tid = threadIdx.x, wv = tid >> 6, ln = tid & 63;
    const float* phr = ph + (size_t)m * 512 + ln * 8;
    floatx4 ph0 = *(const floatx4*)phr;
    floatx4 ph1 = *(const floatx4*)(phr + 4);
    const float* vwr = vw + ln * 8;
    floatx4 vw0 = *(const floatx4*)vwr;
    floatx4 vw1 = *(const floatx4*)(vwr + 4);
    for (int li = 0; li < 32; ++li) {
        int ll = wv * 32 + li;
        const float* per = pe + (size_t)(b * 128 + ll) * 512 + ln * 8;
        floatx4 p0 = *(const floatx4*)per;
        floatx4 p1 = *(const floatx4*)(per + 4);
        float s = 0.f;
#pragma unroll
        for (int j = 0; j < 4; ++j) s += vw0[j] * tanh_f(ph0[j] + p0[j]);
#pragma unroll
        for (int j = 0; j < 4; ++j) s += vw1[j] * tanh_f(ph1[j] + p1[j]);
#pragma unroll
        for (int off = 32; off; off >>= 1) s += __shfl_xor(s, off, 64);
        if (ln == 0) logits[((size_t)t * 128 + ll) * 16 + b] = s;
    }
}

// 6. softmax over b (axis=1 of (T,B,L)) -> att_bf16[b][t][l]
__global__ void att_kernel(const float* logits, unsigned short* attb) {
    int t = blockIdx.x, l = threadIdx.x;     // 128 threads
    const float* p = logits + ((size_t)t * 128 + l) * 16;
    float x[16], mx = -1e30f;
#pragma unroll
    for (int j = 0; j < 16; ++j) { x[j] = p[j]; mx = fmaxf(mx, x[j]); }
    float s = 0.f;
#pragma unroll
    for (int j = 0; j < 16; ++j) { x[j] = __expf(x[j] - mx); s += x[j]; }
    float inv = __builtin_amdgcn_rcpf(s);
#pragma unroll
    for (int j = 0; j < 16; ++j)
        attb[((size_t)j * 128 + t) * 128 + l] = f2bf(x[j] * inv);
}

// 7. weighted[b][t][h] = att[b] @ enc[b]  ->  G[b*128+t][512+h]
__global__ void weighted_kernel(const unsigned short* attb, const unsigned short* enctb,
                                unsigned short* Gmat) {
    int b = blockIdx.z;
    floatx4 acc[4] = {{0,0,0,0},{0,0,0,0},{0,0,0,0},{0,0,0,0}};
    int m0 = blockIdx.x * 64, n0 = blockIdx.y * 64;
    gemm64_acc(attb + (size_t)b * 128 * 128, enctb + (size_t)b * 512 * 128,
               m0, n0, 128, 128, 4, acc);
    int tid = threadIdx.x, wv = tid >> 6, ln = tid & 63, colL = ln & 15, q = ln >> 4;
    int mrow = m0 + wv * 16;
#pragma unroll
    for (int nt = 0; nt < 4; ++nt) {
        int col = n0 + nt * 16 + colL;
#pragma unroll
        for (int r = 0; r < 4; ++r)
            Gmat[(size_t)(b * 128 + mrow + q * 4 + r) * KFC + 512 + col] = f2bf(acc[nt][r]);
    }
}

// ============================================================================
// 8. fc GEMM + fused per-row (max, sumexp) partials.
// ============================================================================
__global__ __launch_bounds__(512, 2)
void fc_kernel(const unsigned short* G, const float* fcW, const float* fcb,
               float2* partials) {
    int wgn = blockIdx.x;
    int tid = threadIdx.x, wv = tid >> 6, ln = tid & 63;
    int colL = ln & 15, q = ln >> 4, koff = q * 8;
    int n0 = wgn * 128 + wv * 16;
    const float* wrow = fcW + (size_t)(n0 + colL) * KFC + koff;
    short8 Bf[32];
#pragma unroll
    for (int kb = 0; kb < 32; ++kb) {
        short8 v;
#pragma unroll
        for (int j = 0; j < 8; ++j) v[j] = (short)f2bf(wrow[kb * 32 + j]);
        Bf[kb] = v;
    }
    float cb = fcb[n0 + colL];
    __shared__ float2 pbuf[128][8];

    for (int mb = 0; mb < 16; ++mb) {
        floatx4 acc[8];
#pragma unroll
        for (int mt = 0; mt < 8; ++mt) acc[mt] = (floatx4){0,0,0,0};
        const unsigned short* gbase =
            G + (size_t)(mb * 128 + colL) * KFC + koff;
#pragma unroll
        for (int kb = 0; kb < 32; ++kb) {
#pragma unroll
            for (int mt = 0; mt < 8; ++mt) {
                short8 af = ld8(gbase + (size_t)mt * 16 * KFC + kb * 32);
                acc[mt] = mfma16(af, Bf[kb], acc[mt]);
            }
        }
        __syncthreads();   // pbuf reuse guard vs previous mb's merge
#pragma unroll
        for (int mt = 0; mt < 8; ++mt) {
#pragma unroll
            for (int r = 0; r < 4; ++r) {
                float v = acc[mt][r] + cb;
                float M = v;
#pragma unroll
                for (int off = 1; off < 16; off <<= 1) M = fmaxf(M, __shfl_xor(M, off, 64));
                float e = __expf(v - M);
#pragma unroll
                for (int off = 1; off < 16; off <<= 1) e += __shfl_xor(e, off, 64);
                if (colL == 0) pbuf[mt * 16 + q * 4 + r][wv] = make_float2(M, e);
            }
        }
        __syncthreads();
        if (tid < 128) {   // merge 8 waves -> one partial per (row, WG)
            float2 a = pbuf[tid][0];
            float M = a.x, S = a.y;
#pragma unroll
            for (int w = 1; w < 8; ++w) {
                float2 p = pbuf[tid][w];
                float nm = fmaxf(M, p.x);
                S = S * __expf(M - nm) + p.y * __expf(p.x - nm);
                M = nm;
            }
            partials[(size_t)(mb * 128 + tid) * 250 + wgn] = make_float2(M, S);
        }
    }
}

// 9. target logit per row: z_y = G[r] . fc_W[y] + fc_b[y]
__global__ void tgt_kernel(const unsigned short* G, const float* fcW, const float* fcb,
                           const int* X, float* tgt) {
    int r = blockIdx.x * 4 + (threadIdx.x >> 6);
    int ln = threadIdx.x & 63;
    int b = r >> 7, t = r & 127;
    int y = X[b * 129 + t + 1];
    y = (y < 0) ? 0 : ((y >= VOCAB) ? VOCAB - 1 : y);   // defensive
    const unsigned short* g = G + (size_t)r * KFC;
    const float* w = fcW + (size_t)y * KFC;
    float s = 0.f;
    for (int j = ln; j < KFC; j += 64) s += bf2f(g[j]) * w[j];
#pragma unroll
    for (int off = 32; off; off >>= 1) s += __shfl_xor(s, off, 64);
    if (ln == 0) tgt[r] = s + fcb[y];
}

// 10. merge partials -> logsumexp -> masked mean NLL
__global__ void finalize_kernel(const float2* partials, const float* tgt,
                                const int* X, float* out) {
    int tid = threadIdx.x;
    float vs = 0.f, vc = 0.f;
    for (int r = tid; r < NROW; r += 256) {
        const float2* p = partials + (size_t)r * 250;
        float M = p[0].x, S = p[0].y;
        for (int i = 1; i < 250; ++i) {
            float2 qq = p[i];
            float nm = fmaxf(M, qq.x);
            S = S * __expf(M - nm) + qq.y * __expf(qq.x - nm);
            M = nm;
        }
        float lse = M + __logf(S);
        int b = r >> 7, t = r & 127;
        int y = X[b * 129 + t + 1];
        if (y != 0) { vs += lse - tgt[r]; vc += 1.f; }
    }
    __shared__ float sv[256], sc[256];
    sv[tid] = vs; sc[tid] = vc;
    __syncthreads();
    for (int s = 128; s; s >>= 1) {
        if (tid < s) { sv[tid] += sv[tid + s]; sc[tid] += sc[tid + s]; }
        __syncthreads();
    }
    if (tid == 0) out[0] = sv[0] / sc[0];
}

// ============================================================================
// launcher
// ============================================================================
extern "C" void kernel_launch(void* const* d_in, const int* in_sizes, int n_in,
                              void* d_out, int out_size, void* d_ws, size_t ws_size,
                              hipStream_t stream) {
    const int*   X     = (const int*)d_in[0];
    const float* enc   = (const float*)d_in[2];
    const float* emb   = (const float*)d_in[3];
    const float* Wih0  = (const float*)d_in[4];
    const float* Whh0  = (const float*)d_in[5];
    const float* bih0  = (const float*)d_in[6];
    const float* bhh0  = (const float*)d_in[7];
    const float* Wih1  = (const float*)d_in[8];
    const float* Whh1  = (const float*)d_in[9];
    const float* bih1  = (const float*)d_in[10];
    const float* bhh1  = (const float*)d_in[11];
    const float* attnW = (const float*)d_in[12];
    const float* attnb = (const float*)d_in[13];
    const float* vw    = (const float*)d_in[14];
    const float* fcW   = (const float*)d_in[15];
    const float* fcb   = (const float*)d_in[16];
    const float* h0    = (const float*)d_in[17];
    const float* c0    = (const float*)d_in[18];

    char* ws = (char*)d_ws;
    size_t off = 0;
    auto take = [&](size_t bytes) { char* p = ws + off; off += (bytes + 255) & ~(size_t)255; return p; };
    int*            ctrl    = (int*)           take(256);
    unsigned short* wih0b   = (unsigned short*)take(2097152);
    unsigned short* whh0b   = (unsigned short*)take(2097152);
    unsigned short* wih1b   = (unsigned short*)take(2097152);
    unsigned short* whh1b   = (unsigned short*)take(2097152);
    unsigned short* whb     = (unsigned short*)take(524288);
    unsigned short* web     = (unsigned short*)take(524288);
    unsigned short* encb    = (unsigned short*)take(2097152);
    unsigned short* enctb   = (unsigned short*)take(2097152);
    unsigned short* xsb     = (unsigned short*)take(2097152);
    unsigned short* h0buf   = (unsigned short*)take(32768);
    unsigned short* h1buf   = (unsigned short*)take(32768);
    unsigned short* A0b     = (unsigned short*)take(8388608);
    unsigned short* hallb   = (unsigned short*)take(2097152);
    unsigned short* gmat    = (unsigned short*)take(4194304);
    float*          ph      = (float*)         take(4194304);
    float*          pe      = (float*)         take(4194304);
    float*          logitsb = (float*)         take(1048576);
    unsigned short* attb    = (unsigned short*)take(524288);
    float2*         parts   = (float2*)        take(4096000);
    float*          tgt     = (float*)         take(8192);
    size_t need = off;
    (void)in_sizes; (void)n_in;

    if (ws_size < need) {
        // Not enough scratch: fail visibly (absmax error) instead of faulting.
        hipLaunchKernelGGL(zero_out_kernel, dim3((out_size + 63) / 64), dim3(64),
                           0, stream, (float*)d_out, out_size);
        return;
    }

    hipLaunchKernelGGL(prep_kernel, dim3(30784), dim3(256), 0, stream,
                       X, enc, emb, Wih0, Whh0, Wih1, Whh1, attnW, h0,
                       wih0b, whh0b, wih1b, whh1b, whb, web, encb, enctb,
                       xsb, h0buf, h1buf, ctrl);
    hipLaunchKernelGGL(a0_kernel, dim3(32, 32), dim3(256), 0, stream,
                       xsb, wih0b, bih0, bhh0, A0b);
    hipLaunchKernelGGL(lstm_kernel, dim3(64), dim3(256), 0, stream,
                       A0b, whh0b, wih1b, whh1b, bih1, bhh1, c0,
                       h0buf, h1buf, hallb, gmat, ctrl);
    hipLaunchKernelGGL(phpe_kernel, dim3(32, 8, 2), dim3(256), 0, stream,
                       hallb, encb, whb, web, attnb, ph, pe);
    hipLaunchKernelGGL(logits_kernel, dim3(2048), dim3(256), 0, stream,
                       ph, pe, vw, logitsb);
    hipLaunchKernelGGL(att_kernel, dim3(128), dim3(128), 0, stream,
                       logitsb, attb);
    hipLaunchKernelGGL(weighted_kernel, dim3(2, 8, 16), dim3(256), 0, stream,
                       attb, enctb, gmat);
    hipLaunchKernelGGL(fc_kernel, dim3(250), dim3(512), 0, stream,
                       gmat, fcW, fcb, parts);
    hipLaunchKernelGGL(tgt_kernel, dim3(512), dim3(256), 0, stream,
                       gmat, fcW, fcb, X, tgt);
    hipLaunchKernelGGL(finalize_kernel, dim3(1), dim3(256), 0, stream,
                       parts, tgt, X, (float*)d_out);
}

// Round 5
// 3141.658 us; speedup vs baseline: 1.4454x; 1.1468x over previous
//
#include <hip/hip_runtime.h>

// ============================================================================
// DecoderGenerator: 2-layer LSTM decoder + additive attention + big vocab
// projection + NLL, fully fused on-device.
//
//   1. prep_kernel     : bf16-cast weights/enc, gather embeddings, transpose
//                        enc, init h-state buffers, zero barrier flags.
//   2. a0_kernel       : A0 = xs @ W_ih0^T + b  (hoisted layer-0 input GEMM)
//   3. lstm_kernel     : persistent 32-WG x 512-thread kernel, 129 ticks.
//                        ROUND 5: L0+L1 merged per WG (shared h0 staging),
//                        per-WG monotonic tick-flag barrier (no RMW chain),
//                        A0 prefetched across the barrier wait.
//   4. phpe_kernel     : ph = Hall@Wh^T ; pe = enc@We^T + attn_b
//   5. logits_kernel   : logits[t,b,l] = sum_k v_w[k] tanh(ph+pe)
//   6. att_kernel      : softmax over b (axis=1 of (T,B,L) — per reference!)
//   7. weighted_kernel : weighted = att @ enc  (per-batch GEMM) -> G[:,512:]
//   8. fc_kernel       : fused GEMM (G @ fc_W^T) + per-row (max,sumexp)
//   9. tgt_kernel      : target logits z_y per row
//  10. finalize_kernel : logsumexp merge + masked-mean NLL -> d_out[0]
// ============================================================================

#define DI __device__ __forceinline__

typedef __attribute__((ext_vector_type(8))) short short8;
typedef __attribute__((ext_vector_type(4))) float floatx4;

#define TSEQ   128
#define VOCAB  32000
#define GDIM   2048   // 4*H
#define NROW   2048   // B*T
#define KFC    1024   // 2*H
#define HPAD   520    // LDS row stride for h staging (512 + 8 pad)

// ---------------- small helpers ----------------
DI float bf2f(unsigned short u) {
    union { unsigned u; float f; } x; x.u = ((unsigned)u) << 16; return x.f;
}
DI unsigned short f2bf(float f) {   // RNE float -> bf16
    unsigned u = __float_as_uint(f);
    unsigned r = (u + 0x7FFF + ((u >> 16) & 1)) >> 16;
    return (unsigned short)r;
}
DI short8 ld8(const unsigned short* p) { return *(const short8*)p; }
DI floatx4 mfma16(short8 a, short8 b, floatx4 c) {
    return __builtin_amdgcn_mfma_f32_16x16x32_bf16(a, b, c, 0, 0, 0);
}
DI float sigm(float x) { return __builtin_amdgcn_rcpf(1.f + __expf(-x)); }
DI float tanh_f(float x) {
    float xc = fminf(8.f, fmaxf(-8.f, x));
    float e  = __expf(2.f * xc);
    return (e - 1.f) * __builtin_amdgcn_rcpf(e + 1.f);
}

// ---------------- barrier: per-WG monotonic tick flags --------------------
// flags[wg*32]: WG wg's last published tick (separate 128B cache lines).
// Publish: one release store per WG (parallel, no RMW chain).
// Detect: lanes 0..31 of wave 0 each poll one flag -> one LLC round trip.
DI void gbar32(int* flags, int target) {
    __threadfence();            // make this WG's h-stores agent-visible
    __syncthreads();
    if (threadIdx.x == 0)
        __hip_atomic_store(flags + (int)blockIdx.x * 32, target,
                           __ATOMIC_RELEASE, __HIP_MEMORY_SCOPE_AGENT);
    if (threadIdx.x < 32) {
        int guard = 0;
        while (__hip_atomic_load(flags + threadIdx.x * 32,
                                 __ATOMIC_ACQUIRE, __HIP_MEMORY_SCOPE_AGENT) < target) {
            __builtin_amdgcn_s_sleep(1);
            if (++guard > (1 << 22)) break;   // fail loud, not hung
        }
    }
    __syncthreads();
    __threadfence();            // acquire side for all threads
}

// fallback path: make the failure visible instead of faulting
__global__ void zero_out_kernel(float* out, int n) {
    int i = blockIdx.x * 64 + threadIdx.x;
    if (i < n) out[i] = 0.f;
}

// ============================================================================
// 1. prep kernel : segmented grid-stride over all conversion jobs
//    total work = 4*1048576 + 2*262144 + 3*1048576 + 16384 = 7,880,704
//    grid = 30,784 blocks x 256.
// ============================================================================
__global__ void prep_kernel(const int* X, const float* enc, const float* emb,
                            const float* Wih0, const float* Whh0,
                            const float* Wih1, const float* Whh1,
                            const float* attnW, const float* h0,
                            unsigned short* wih0b, unsigned short* whh0b,
                            unsigned short* wih1b, unsigned short* whh1b,
                            unsigned short* whb, unsigned short* web,
                            unsigned short* encb, unsigned short* enctb,
                            unsigned short* xsb,
                            unsigned short* h0buf, unsigned short* h1buf,
                            int* ctrl) {
    if (blockIdx.x == 0) {              // zero all 1024 flag ints
#pragma unroll
        for (int j = 0; j < 4; ++j) ctrl[threadIdx.x + 256 * j] = 0;
    }
    long i = (long)blockIdx.x * 256 + threadIdx.x;
    const long NW = 1048576;
    const long NA = 262144;            // 512x512 half of attn_W
    if (i < NW) { wih0b[i] = f2bf(Wih0[i]); return; } i -= NW;
    if (i < NW) { whh0b[i] = f2bf(Whh0[i]); return; } i -= NW;
    if (i < NW) { wih1b[i] = f2bf(Wih1[i]); return; } i -= NW;
    if (i < NW) { whh1b[i] = f2bf(Whh1[i]); return; } i -= NW;
    if (i < NA) { long k = i >> 9, h = i & 511; whb[i] = f2bf(attnW[k * 1024 + h]);       return; } i -= NA;
    if (i < NA) { long k = i >> 9, h = i & 511; web[i] = f2bf(attnW[k * 1024 + 512 + h]); return; } i -= NA;
    if (i < NW) { encb[i] = f2bf(enc[i]); return; } i -= NW;
    if (i < NW) {  // enc_t[b][h][l] = enc[b][l][h]
        long b = i >> 16, r = i & 65535, h = r >> 7, l = r & 127;
        enctb[i] = f2bf(enc[(b * 128 + l) * 512 + h]); return;
    } i -= NW;
    if (i < NW) {  // xs[t*16+b][e] = emb[X[b][t]][e]
        long m = i >> 9, e = i & 511, t = m >> 4, b = m & 15;
        int xi = X[b * 129 + t];
        xi = (xi < 0) ? 0 : ((xi >= VOCAB) ? VOCAB - 1 : xi);   // defensive
        xsb[i] = f2bf(emb[(long)xi * 512 + e]); return;
    } i -= NW;
    if (i < 16384) {  // h inits into parity-1 buffers
        long layer = i >> 13, r = i & 8191;
        unsigned short v = f2bf(h0[layer * 8192 + r]);
        if (layer == 0) h0buf[8192 + r] = v; else h1buf[8192 + r] = v;
    }
}

// ============================================================================
// shared 64x64 MFMA tile: C[m0..+63][n0..+63] += A(m,k) * B(n,k)^T
// ============================================================================
DI void gemm64_acc(const unsigned short* A, const unsigned short* Bw,
                   int m0, int n0, int lda, int ldb, int nkb, floatx4 acc[4]) {
    int tid = threadIdx.x;
    int wv = tid >> 6, ln = tid & 63;
    int colL = ln & 15, koff = (ln >> 4) * 8;
    const unsigned short* ar  = A  + (size_t)(m0 + wv * 16 + colL) * lda + koff;
    const unsigned short* br0 = Bw + (size_t)(n0 +  0 + colL) * ldb + koff;
    const unsigned short* br1 = Bw + (size_t)(n0 + 16 + colL) * ldb + koff;
    const unsigned short* br2 = Bw + (size_t)(n0 + 32 + colL) * ldb + koff;
    const unsigned short* br3 = Bw + (size_t)(n0 + 48 + colL) * ldb + koff;
    for (int kb = 0; kb < nkb; ++kb) {
        short8 af = ld8(ar + kb * 32);
        acc[0] = mfma16(af, ld8(br0 + kb * 32), acc[0]);
        acc[1] = mfma16(af, ld8(br1 + kb * 32), acc[1]);
        acc[2] = mfma16(af, ld8(br2 + kb * 32), acc[2]);
        acc[3] = mfma16(af, ld8(br3 + kb * 32), acc[3]);
    }
}

// 2. A0 = xs @ W_ih0^T + (b_ih0 + b_hh0), stored bf16 (bias folded)
__global__ void a0_kernel(const unsigned short* xs, const unsigned short* wih0b,
                          const float* bih0, const float* bhh0, unsigned short* A0b) {
    floatx4 acc[4] = {{0,0,0,0},{0,0,0,0},{0,0,0,0},{0,0,0,0}};
    int m0 = blockIdx.x * 64, n0 = blockIdx.y * 64;
    gemm64_acc(xs, wih0b, m0, n0, 512, 512, 16, acc);
    int tid = threadIdx.x, wv = tid >> 6, ln = tid & 63, colL = ln & 15, q = ln >> 4;
    int mrow = m0 + wv * 16;
#pragma unroll
    for (int nt = 0; nt < 4; ++nt) {
        int col = n0 + nt * 16 + colL;
        float bb = bih0[col] + bhh0[col];
#pragma unroll
        for (int r = 0; r < 4; ++r)
            A0b[(size_t)(mrow + q * 4 + r) * GDIM + col] = f2bf(acc[nt][r] + bb);
    }
}

// ============================================================================
// 3. persistent LSTM kernel.  32 WGs x 512 threads.
//    Per WG: threads 0..255 = layer0 slice (units u0..u0+15),
//            threads 256..511 = layer1 slice (same units).
//    tick t: L0 half computes h0[t] (t<128), L1 half computes h1[t-1] (t>=1).
//    Both halves consume the SAME staged h0[t-1]; L1 also stages h1[t-2].
//    One flag-barrier per tick; weights VGPR-resident.
// ============================================================================
__global__ __launch_bounds__(512, 1)
void lstm_kernel(const unsigned short* A0b,
                 const unsigned short* whh0b, const unsigned short* wih1b,
                 const unsigned short* whh1b,
                 const float* bih1, const float* bhh1, const float* c0in,
                 unsigned short* h0buf, unsigned short* h1buf,
                 unsigned short* Hall, unsigned short* Gmat, int* flags) {
    __shared__ unsigned short hsh0[16 * HPAD];   // h0[t-1], shared by both halves
    __shared__ unsigned short hsh1[16 * HPAD];   // h1[t-2], L1 half only
    __shared__ float gbuf[2][4][16][16];         // [half][gate][batch][unit]
    int wg = blockIdx.x;            // 0..31
    int tid = threadIdx.x;          // 0..511
    int half = tid >> 8;            // 0 = L0, 1 = L1
    int lt   = tid & 255;
    int wv = lt >> 6, ln = lt & 63;
    int u0 = wg * 16;
    int n0 = wv * 512 + u0;         // gate column base (wave-of-half = gate)
    int colL = ln & 15, q = ln >> 4, koff = q * 8;
    int eb = lt >> 4, eu = lt & 15; // elementwise mapping within half
    float c = c0in[half * 8192 + eb * 512 + u0 + eu];
    float bias1 = (half == 1) ? (bih1[n0 + colL] + bhh1[n0 + colL]) : 0.f;

    // ---- one-time: weight slices into registers (128 VGPRs) ----
    short8 wA[16], wB[16];
    if (half == 0) {
        const unsigned short* wr0 = whh0b + (size_t)(n0 + colL) * 512 + koff;
#pragma unroll
        for (int kb = 0; kb < 16; ++kb) wA[kb] = ld8(wr0 + kb * 32);
#pragma unroll
        for (int kb = 0; kb < 16; ++kb) wB[kb] = wA[kb];   // unused, keep defined
    } else {
        const unsigned short* wr1 = wih1b + (size_t)(n0 + colL) * 512 + koff;
        const unsigned short* wr2 = whh1b + (size_t)(n0 + colL) * 512 + koff;
#pragma unroll
        for (int kb = 0; kb < 16; ++kb) wA[kb] = ld8(wr1 + kb * 32);
#pragma unroll
        for (int kb = 0; kb < 16; ++kb) wB[kb] = ld8(wr2 + kb * 32);
    }

    // A0 prefetch for tick 0 (L0 half)
    floatx4 a0pre;
    if (half == 0) {
        const unsigned short* a0r = A0b + (size_t)(0 * 16) * GDIM + n0 + colL;
        a0pre[0] = bf2f(a0r[(q * 4 + 0) * GDIM]);
        a0pre[1] = bf2f(a0r[(q * 4 + 1) * GDIM]);
        a0pre[2] = bf2f(a0r[(q * 4 + 2) * GDIM]);
        a0pre[3] = bf2f(a0r[(q * 4 + 3) * GDIM]);
    }

#pragma unroll 1
    for (int t = 0; t <= TSEQ; ++t) {
        bool actL0 = (t < TSEQ);
        bool actL1 = (t >= 1);
        // ---- stage h vectors global -> LDS (whole WG cooperates) ----
        {
            const unsigned short* s0 = h0buf + ((t - 1) & 1) * 8192;
#pragma unroll
            for (int j = 0; j < 4; ++j) {
                int idx = (j * 512 + tid) * 8;
                *(short8*)&hsh0[(idx >> 9) * HPAD + (idx & 511)] = ld8(s0 + idx);
            }
            if (actL1) {
                const unsigned short* s1 = h1buf + ((t - 2) & 1) * 8192;   // h1[t-2]
#pragma unroll
                for (int j = 0; j < 4; ++j) {
                    int idx = (j * 512 + tid) * 8;
                    *(short8*)&hsh1[(idx >> 9) * HPAD + (idx & 511)] = ld8(s1 + idx);
                }
            }
        }
        __syncthreads();
        // ---- MFMA: LDS fragments x register weights ----
        bool act = half ? actL1 : actL0;
        if (act) {
            floatx4 acc;
            const unsigned short* hl0 = hsh0 + colL * HPAD + koff;
            if (half == 0) {
                acc = a0pre;
#pragma unroll
                for (int kb = 0; kb < 16; ++kb)
                    acc = mfma16(ld8(hl0 + kb * 32), wA[kb], acc);
            } else {
                acc[0] = bias1; acc[1] = bias1; acc[2] = bias1; acc[3] = bias1;
                const unsigned short* hl1 = hsh1 + colL * HPAD + koff;
#pragma unroll
                for (int kb = 0; kb < 16; ++kb)
                    acc = mfma16(ld8(hl0 + kb * 32), wA[kb], acc);
#pragma unroll
                for (int kb = 0; kb < 16; ++kb)
                    acc = mfma16(ld8(hl1 + kb * 32), wB[kb], acc);
            }
            // D layout: row = batch = q*4+r, col = unit = colL
            gbuf[half][wv][q * 4 + 0][colL] = acc[0];
            gbuf[half][wv][q * 4 + 1][colL] = acc[1];
            gbuf[half][wv][q * 4 + 2][colL] = acc[2];
            gbuf[half][wv][q * 4 + 3][colL] = acc[3];
        }
        __syncthreads();
        if (act) {
            float gi = gbuf[half][0][eb][eu], gf = gbuf[half][1][eb][eu];
            float gg = gbuf[half][2][eb][eu], go = gbuf[half][3][eb][eu];
            float c2 = sigm(gf) * c + sigm(gi) * tanh_f(gg);
            float h2 = sigm(go) * tanh_f(c2);
            c = c2;
            unsigned short hb = f2bf(h2);
            if (half == 0) {
                h0buf[(t & 1) * 8192 + eb * 512 + u0 + eu] = hb;
            } else {
                int s = t - 1;
                h1buf[(s & 1) * 8192 + eb * 512 + u0 + eu] = hb;
                Hall[(size_t)(s * 16 + eb) * 512 + u0 + eu] = hb;           // [t*16+b][u]
                Gmat[(size_t)(eb * 128 + s) * KFC + u0 + eu] = hb;          // [b*128+t][u]
            }
        }
        // ---- prefetch next tick's A0 (overlaps the barrier wait) ----
        if (half == 0 && t + 1 < TSEQ) {
            const unsigned short* a0r = A0b + (size_t)((t + 1) * 16) * GDIM + n0 + colL;
            a0pre[0] = bf2f(a0r[(q * 4 + 0) * GDIM]);
            a0pre[1] = bf2f(a0r[(q * 4 + 1) * GDIM]);
            a0pre[2] = bf2f(a0r[(q * 4 + 2) * GDIM]);
            a0pre[3] = bf2f(a0r[(q * 4 + 3) * GDIM]);
        }
        if (t < TSEQ) gbar32(flags, t + 1);   // final tick needs no barrier
    }
}

// 4. ph = Hall @ Wh^T ; pe = enc @ We^T + attn_b   (z selects)
__global__ void phpe_kernel(const unsigned short* Hall, const unsigned short* encb,
                            const unsigned short* whb, const unsigned short* web,
                            const float* attnb, float* ph, float* pe) {
    bool ispe = (blockIdx.z != 0);
    const unsigned short* A  = ispe ? encb : Hall;
    const unsigned short* Bw = ispe ? web  : whb;
    float* out = ispe ? pe : ph;
    floatx4 acc[4] = {{0,0,0,0},{0,0,0,0},{0,0,0,0},{0,0,0,0}};
    int m0 = blockIdx.x * 64, n0 = blockIdx.y * 64;
    gemm64_acc(A, Bw, m0, n0, 512, 512, 16, acc);
    int tid = threadIdx.x, wv = tid >> 6, ln = tid & 63, colL = ln & 15, q = ln >> 4;
    int mrow = m0 + wv * 16;
#pragma unroll
    for (int nt = 0; nt < 4; ++nt) {
        int col = n0 + nt * 16 + colL;
        float bb = ispe ? attnb[col] : 0.f;
#pragma unroll
        for (int r = 0; r < 4; ++r)
            out[(size_t)(mrow + q * 4 + r) * 512 + col] = acc[nt][r] + bb;
    }
}

// 5. logits[t][l][b] = sum_k v_w[k] * tanh(ph[t*16+b][k] + pe[b*128+l][k])
__global__ void logits_kernel(const float* ph, const float* pe, const float* vw,
                              float* logits) {
    int m = blockIdx.x;             // t*16+b
    int t = m >> 4, b = m & 15;
    int tid = threadIdx.x, wv = tid >> 6, ln = tid & 63;
    const float* phr = ph + (size_t)m * 512 + ln * 8;
    floatx4 ph0 = *(const floatx4*)phr;
    floatx4 ph1 = *(const floatx4*)(phr + 4);
    const float* vwr = vw + ln * 8;
    floatx4 vw0 = *(const floatx4*)vwr;
    floatx4 vw1 = *(const floatx4*)(vwr + 4);
    for (int li = 0; li < 32; ++li) {
        int ll = wv * 32 + li;
        const float* per = pe + (size_t)(b * 128 + ll) * 512 + ln * 8;
        floatx4 p0 = *(const floatx4*)per;
        floatx4 p1 = *(const floatx4*)(per + 4);
        float s = 0.f;
#pragma unroll
        for (int j = 0; j < 4; ++j) s += vw0[j] * tanh_f(ph0[j] + p0[j]);
#pragma unroll
        for (int j = 0; j < 4; ++j) s += vw1[j] * tanh_f(ph1[j] + p1[j]);
#pragma unroll
        for (int off = 32; off; off >>= 1) s += __shfl_xor(s, off, 64);
        if (ln == 0) logits[((size_t)t * 128 + ll) * 16 + b] = s;
    }
}

// 6. softmax over b (axis=1 of (T,B,L)) -> att_bf16[b][t][l]
__global__ void att_kernel(const float* logits, unsigned short* attb) {
    int t = blockIdx.x, l = threadIdx.x;     // 128 threads
    const float* p = logits + ((size_t)t * 128 + l) * 16;
    float x[16], mx = -1e30f;
#pragma unroll
    for (int j = 0; j < 16; ++j) { x[j] = p[j]; mx = fmaxf(mx, x[j]); }
    float s = 0.f;
#pragma unroll
    for (int j = 0; j < 16; ++j) { x[j] = __expf(x[j] - mx); s += x[j]; }
    float inv = __builtin_amdgcn_rcpf(s);
#pragma unroll
    for (int j = 0; j < 16; ++j)
        attb[((size_t)j * 128 + t) * 128 + l] = f2bf(x[j] * inv);
}

// 7. weighted[b][t][h] = att[b] @ enc[b]  ->  G[b*128+t][512+h]
__global__ void weighted_kernel(const unsigned short* attb, const unsigned short* enctb,
                                unsigned short* Gmat) {
    int b = blockIdx.z;
    floatx4 acc[4] = {{0,0,0,0},{0,0,0,0},{0,0,0,0},{0,0,0,0}};
    int m0 = blockIdx.x * 64, n0 = blockIdx.y * 64;
    gemm64_acc(attb + (size_t)b * 128 * 128, enctb + (size_t)b * 512 * 128,
               m0, n0, 128, 128, 4, acc);
    int tid = threadIdx.x, wv = tid >> 6, ln = tid & 63, colL = ln & 15, q = ln >> 4;
    int mrow = m0 + wv * 16;
#pragma unroll
    for (int nt = 0; nt < 4; ++nt) {
        int col = n0 + nt * 16 + colL;
#pragma unroll
        for (int r = 0; r < 4; ++r)
            Gmat[(size_t)(b * 128 + mrow + q * 4 + r) * KFC + 512 + col] = f2bf(acc[nt][r]);
    }
}

// ============================================================================
// 8. fc GEMM + fused per-row (max, sumexp) partials.
// ============================================================================
__global__ __launch_bounds__(512, 2)
void fc_kernel(const unsigned short* G, const float* fcW, const float* fcb,
               float2* partials) {
    int wgn = blockIdx.x;
    int tid = threadIdx.x, wv = tid >> 6, ln = tid & 63;
    int colL = ln & 15, q = ln >> 4, koff = q * 8;
    int n0 = wgn * 128 + wv * 16;
    const float* wrow = fcW + (size_t)(n0 + colL) * KFC + koff;
    short8 Bf[32];
#pragma unroll
    for (int kb = 0; kb < 32; ++kb) {
        short8 v;
#pragma unroll
        for (int j = 0; j < 8; ++j) v[j] = (short)f2bf(wrow[kb * 32 + j]);
        Bf[kb] = v;
    }
    float cb = fcb[n0 + colL];
    __shared__ float2 pbuf[128][8];

    for (int mb = 0; mb < 16; ++mb) {
        floatx4 acc[8];
#pragma unroll
        for (int mt = 0; mt < 8; ++mt) acc[mt] = (floatx4){0,0,0,0};
        const unsigned short* gbase =
            G + (size_t)(mb * 128 + colL) * KFC + koff;
#pragma unroll
        for (int kb = 0; kb < 32; ++kb) {
#pragma unroll
            for (int mt = 0; mt < 8; ++mt) {
                short8 af = ld8(gbase + (size_t)mt * 16 * KFC + kb * 32);
                acc[mt] = mfma16(af, Bf[kb], acc[mt]);
            }
        }
        __syncthreads();   // pbuf reuse guard vs previous mb's merge
#pragma unroll
        for (int mt = 0; mt < 8; ++mt) {
#pragma unroll
            for (int r = 0; r < 4; ++r) {
                float v = acc[mt][r] + cb;
                float M = v;
#pragma unroll
                for (int off = 1; off < 16; off <<= 1) M = fmaxf(M, __shfl_xor(M, off, 64));
                float e = __expf(v - M);
#pragma unroll
                for (int off = 1; off < 16; off <<= 1) e += __shfl_xor(e, off, 64);
                if (colL == 0) pbuf[mt * 16 + q * 4 + r][wv] = make_float2(M, e);
            }
        }
        __syncthreads();
        if (tid < 128) {   // merge 8 waves -> one partial per (row, WG)
            float2 a = pbuf[tid][0];
            float M = a.x, S = a.y;
#pragma unroll
            for (int w = 1; w < 8; ++w) {
                float2 p = pbuf[tid][w];
                float nm = fmaxf(M, p.x);
                S = S * __expf(M - nm) + p.y * __expf(p.x - nm);
                M = nm;
            }
            partials[(size_t)(mb * 128 + tid) * 250 + wgn] = make_float2(M, S);
        }
    }
}

// 9. target logit per row: z_y = G[r] . fc_W[y] + fc_b[y]
__global__ void tgt_kernel(const unsigned short* G, const float* fcW, const float* fcb,
                           const int* X, float* tgt) {
    int r = blockIdx.x * 4 + (threadIdx.x >> 6);
    int ln = threadIdx.x & 63;
    int b = r >> 7, t = r & 127;
    int y = X[b * 129 + t + 1];
    y = (y < 0) ? 0 : ((y >= VOCAB) ? VOCAB - 1 : y);   // defensive
    const unsigned short* g = G + (size_t)r * KFC;
    const float* w = fcW + (size_t)y * KFC;
    float s = 0.f;
    for (int j = ln; j < KFC; j += 64) s += bf2f(g[j]) * w[j];
#pragma unroll
    for (int off = 32; off; off >>= 1) s += __shfl_xor(s, off, 64);
    if (ln == 0) tgt[r] = s + fcb[y];
}

// 10. merge partials -> logsumexp -> masked mean NLL
__global__ void finalize_kernel(const float2* partials, const float* tgt,
                                const int* X, float* out) {
    int tid = threadIdx.x;
    float vs = 0.f, vc = 0.f;
    for (int r = tid; r < NROW; r += 256) {
        const float2* p = partials + (size_t)r * 250;
        float M = p[0].x, S = p[0].y;
        for (int i = 1; i < 250; ++i) {
            float2 qq = p[i];
            float nm = fmaxf(M, qq.x);
            S = S * __expf(M - nm) + qq.y * __expf(qq.x - nm);
            M = nm;
        }
        float lse = M + __logf(S);
        int b = r >> 7, t = r & 127;
        int y = X[b * 129 + t + 1];
        if (y != 0) { vs += lse - tgt[r]; vc += 1.f; }
    }
    __shared__ float sv[256], sc[256];
    sv[tid] = vs; sc[tid] = vc;
    __syncthreads();
    for (int s = 128; s; s >>= 1) {
        if (tid < s) { sv[tid] += sv[tid + s]; sc[tid] += sc[tid + s]; }
        __syncthreads();
    }
    if (tid == 0) out[0] = sv[0] / sc[0];
}

// ============================================================================
// launcher
// ============================================================================
extern "C" void kernel_launch(void* const* d_in, const int* in_sizes, int n_in,
                              void* d_out, int out_size, void* d_ws, size_t ws_size,
                              hipStream_t stream) {
    const int*   X     = (const int*)d_in[0];
    const float* enc   = (const float*)d_in[2];
    const float* emb   = (const float*)d_in[3];
    const float* Wih0  = (const float*)d_in[4];
    const float* Whh0  = (const float*)d_in[5];
    const float* bih0  = (const float*)d_in[6];
    const float* bhh0  = (const float*)d_in[7];
    const float* Wih1  = (const float*)d_in[8];
    const float* Whh1  = (const float*)d_in[9];
    const float* bih1  = (const float*)d_in[10];
    const float* bhh1  = (const float*)d_in[11];
    const float* attnW = (const float*)d_in[12];
    const float* attnb = (const float*)d_in[13];
    const float* vw    = (const float*)d_in[14];
    const float* fcW   = (const float*)d_in[15];
    const float* fcb   = (const float*)d_in[16];
    const float* h0    = (const float*)d_in[17];
    const float* c0    = (const float*)d_in[18];

    char* ws = (char*)d_ws;
    size_t off = 0;
    auto take = [&](size_t bytes) { char* p = ws + off; off += (bytes + 255) & ~(size_t)255; return p; };
    int*            ctrl    = (int*)           take(4096);
    unsigned short* wih0b   = (unsigned short*)take(2097152);
    unsigned short* whh0b   = (unsigned short*)take(2097152);
    unsigned short* wih1b   = (unsigned short*)take(2097152);
    unsigned short* whh1b   = (unsigned short*)take(2097152);
    unsigned short* whb     = (unsigned short*)take(524288);
    unsigned short* web     = (unsigned short*)take(524288);
    unsigned short* encb    = (unsigned short*)take(2097152);
    unsigned short* enctb   = (unsigned short*)take(2097152);
    unsigned short* xsb     = (unsigned short*)take(2097152);
    unsigned short* h0buf   = (unsigned short*)take(32768);
    unsigned short* h1buf   = (unsigned short*)take(32768);
    unsigned short* A0b     = (unsigned short*)take(8388608);
    unsigned short* hallb   = (unsigned short*)take(2097152);
    unsigned short* gmat    = (unsigned short*)take(4194304);
    float*          ph      = (float*)         take(4194304);
    float*          pe      = (float*)         take(4194304);
    float*          logitsb = (float*)         take(1048576);
    unsigned short* attb    = (unsigned short*)take(524288);
    float2*         parts   = (float2*)        take(4096000);
    float*          tgt     = (float*)         take(8192);
    size_t need = off;
    (void)in_sizes; (void)n_in;

    if (ws_size < need) {
        // Not enough scratch: fail visibly (absmax error) instead of faulting.
        hipLaunchKernelGGL(zero_out_kernel, dim3((out_size + 63) / 64), dim3(64),
                           0, stream, (float*)d_out, out_size);
        return;
    }

    hipLaunchKernelGGL(prep_kernel, dim3(30784), dim3(256), 0, stream,
                       X, enc, emb, Wih0, Whh0, Wih1, Whh1, attnW, h0,
                       wih0b, whh0b, wih1b, whh1b, whb, web, encb, enctb,
                       xsb, h0buf, h1buf, ctrl);
    hipLaunchKernelGGL(a0_kernel, dim3(32, 32), dim3(256), 0, stream,
                       xsb, wih0b, bih0, bhh0, A0b);
    hipLaunchKernelGGL(lstm_kernel, dim3(32), dim3(512), 0, stream,
                       A0b, whh0b, wih1b, whh1b, bih1, bhh1, c0,
                       h0buf, h1buf, hallb, gmat, ctrl);
    hipLaunchKernelGGL(phpe_kernel, dim3(32, 8, 2), dim3(256), 0, stream,
                       hallb, encb, whb, web, attnb, ph, pe);
    hipLaunchKernelGGL(logits_kernel, dim3(2048), dim3(256), 0, stream,
                       ph, pe, vw, logitsb);
    hipLaunchKernelGGL(att_kernel, dim3(128), dim3(128), 0, stream,
                       logitsb, attb);
    hipLaunchKernelGGL(weighted_kernel, dim3(2, 8, 16), dim3(256), 0, stream,
                       attb, enctb, gmat);
    hipLaunchKernelGGL(fc_kernel, dim3(250), dim3(512), 0, stream,
                       gmat, fcW, fcb, parts);
    hipLaunchKernelGGL(tgt_kernel, dim3(512), dim3(256), 0, stream,
                       gmat, fcW, fcb, X, tgt);
    hipLaunchKernelGGL(finalize_kernel, dim3(1), dim3(256), 0, stream,
                       parts, tgt, X, (float*)d_out);
}